// Round 2
// baseline (8012.184 us; speedup 1.0000x reference)
//
#include <hip/hip_runtime.h>
#include <math.h>

#define NV 150000
#define NFACE 300000
#define TILE_V 16
#define BLOCK 256

// LDS arena layout (floats)
#define PIN 9
#define PH 257
#define PG 513
#define PC 126
#define PX 129
#define OFF_IN 0
#define OFF_H 144            // 16*9
#define OFF_G 4256           // 144 + 16*257
#define OFF_CUBE OFF_G
#define OFF_XL (OFF_G + 2016)  // 16*126
#define ARENA 12464          // 4256 + 16*513

__global__ __launch_bounds__(256) void ds_kernel(const float* __restrict__ in,
                                                 float* __restrict__ out, int od) {
  int t = blockIdx.x * 256 + threadIdx.x;
  int tot = od * od * od;
  if (t >= tot) return;
  int oz = t % od; int r = t / od; int oy = r % od; int ox = r / od;
  int id = od * 2;
  size_t base = ((size_t)(2 * ox) * id + (size_t)(2 * oy)) * id + (size_t)(2 * oz);
  float s = 0.f;
  for (int i = 0; i < 2; ++i)
    for (int j = 0; j < 2; ++j)
      for (int k = 0; k < 2; ++k)
        s += in[base + (size_t)i * id * id + (size_t)j * id + k];
  out[t] = s * 0.125f;
}

__global__ __launch_bounds__(256) void face_normals_kernel(const float* __restrict__ x,
                                                           const int* __restrict__ f,
                                                           float* __restrict__ nrm) {
  int i = blockIdx.x * 256 + threadIdx.x;
  if (i >= NFACE) return;
  int a = f[i * 3 + 0], b = f[i * 3 + 1], c = f[i * 3 + 2];
  float ax = x[a * 3 + 0], ay = x[a * 3 + 1], az = x[a * 3 + 2];
  float bx = x[b * 3 + 0], by = x[b * 3 + 1], bz = x[b * 3 + 2];
  float cx = x[c * 3 + 0], cy = x[c * 3 + 1], cz = x[c * 3 + 2];
  float ux = bx - ax, uy = by - ay, uz = bz - az;
  float vx = cx - ax, vy = cy - ay, vz = cz - az;
  float nx = uy * vz - uz * vy;
  float ny = uz * vx - ux * vz;
  float nz = ux * vy - uy * vx;
  atomicAdd(&nrm[a * 3 + 0], nx); atomicAdd(&nrm[a * 3 + 1], ny); atomicAdd(&nrm[a * 3 + 2], nz);
  atomicAdd(&nrm[b * 3 + 0], nx); atomicAdd(&nrm[b * 3 + 1], ny); atomicAdd(&nrm[b * 3 + 2], nz);
  atomicAdd(&nrm[c * 3 + 0], nx); atomicAdd(&nrm[c * 3 + 1], ny); atomicAdd(&nrm[c * 3 + 2], nz);
}

__global__ __launch_bounds__(256) void cnt_kernel(const int* __restrict__ f,
                                                  float* __restrict__ cnt) {
  int i = blockIdx.x * 256 + threadIdx.x;
  if (i >= NFACE) return;
  atomicAdd(&cnt[f[i * 3 + 0]], 1.f);
  atomicAdd(&cnt[f[i * 3 + 1]], 1.f);
  atomicAdd(&cnt[f[i * 3 + 2]], 1.f);
}

__global__ __launch_bounds__(256) void smooth_scatter_kernel(const float* __restrict__ x,
                                                             const int* __restrict__ f,
                                                             float* __restrict__ xs) {
  int i = blockIdx.x * 256 + threadIdx.x;
  if (i >= NFACE) return;
  int a = f[i * 3 + 0], b = f[i * 3 + 1], c = f[i * 3 + 2];
  // edges: src f0 -> dst f1 ; src f1 -> dst f2 ; src f2 -> dst f0
  for (int d = 0; d < 3; ++d) atomicAdd(&xs[b * 3 + d], x[a * 3 + d]);
  for (int d = 0; d < 3; ++d) atomicAdd(&xs[c * 3 + d], x[b * 3 + d]);
  for (int d = 0; d < 3; ++d) atomicAdd(&xs[a * 3 + d], x[c * 3 + d]);
}

__global__ __launch_bounds__(256) void finalize_kernel(const float* __restrict__ xs,
                                                       const float* __restrict__ cnt,
                                                       const float* __restrict__ x,
                                                       const int* __restrict__ nsm,
                                                       float* __restrict__ out) {
  int e = blockIdx.x * 256 + threadIdx.x;
  if (e >= NV * 3) return;
  int ns = nsm[0];
  if (ns >= 1) {
    int v = e / 3;
    float c = fmaxf(cnt[v], 1.f);
    out[e] = xs[e] / c;
  } else {
    out[e] = x[e];
  }
}

__global__ __launch_bounds__(256) void block_kernel(
    float* __restrict__ x,               // in/out positions (in-place per-vertex update)
    const float* __restrict__ nrm,       // raw accumulated normals
    const float* __restrict__ vol0, const float* __restrict__ vol1, const float* __restrict__ vol2,
    const float* __restrict__ fc1w, const float* __restrict__ fc1b,
    const float* __restrict__ convw, const float* __restrict__ convb,
    const float* __restrict__ lfcw, const float* __restrict__ lfcb,
    const float* __restrict__ fc2w, const float* __restrict__ fc2b,
    const float* __restrict__ fc3w, const float* __restrict__ fc3b,
    const float* __restrict__ fc4w, const float* __restrict__ fc4b) {
  __shared__ float S[ARENA];
  float* sIn = S + OFF_IN;     // [16][9]  : x(3), nrm(3)
  float* sH  = S + OFF_H;      // [16][257]: h (256)
  float* sG  = S + OFF_G;      // [16][513]: g (512)
  float* sCube = S + OFF_CUBE; // [16][126]
  float* sXl1  = S + OFF_XL;   // [16][129]

  const int tid = threadIdx.x;
  const int v0 = blockIdx.x * TILE_V;
  const int vg = tid & 3;       // 4 vertex groups of 4
  const int cg = tid >> 2;      // 64 channel groups

  // ---- stage inputs: positions + normalized normals ----
  if (tid < TILE_V) {
    int v = v0 + tid;
    float px = x[v * 3 + 0], py = x[v * 3 + 1], pz = x[v * 3 + 2];
    float nx = nrm[v * 3 + 0], ny = nrm[v * 3 + 1], nz = nrm[v * 3 + 2];
    float nn = sqrtf(nx * nx + ny * ny + nz * nz);
    float d = fmaxf(nn, 1e-12f);
    sIn[tid * PIN + 0] = px; sIn[tid * PIN + 1] = py; sIn[tid * PIN + 2] = pz;
    sIn[tid * PIN + 3] = nx / d; sIn[tid * PIN + 4] = ny / d; sIn[tid * PIN + 5] = nz / d;
  }
  __syncthreads();

  // ---- fc1: 6 -> 128, lrelu, out -> sH[.][0..127]  (2 ch/thread) ----
  {
    float acc[4][2] = {{0.f, 0.f}, {0.f, 0.f}, {0.f, 0.f}, {0.f, 0.f}};
    for (int k = 0; k < 6; ++k) {
      float a0 = sIn[(vg * 4 + 0) * PIN + k];
      float a1 = sIn[(vg * 4 + 1) * PIN + k];
      float a2 = sIn[(vg * 4 + 2) * PIN + k];
      float a3 = sIn[(vg * 4 + 3) * PIN + k];
      for (int j = 0; j < 2; ++j) {
        float w = fc1w[(cg * 2 + j) * 6 + k];
        acc[0][j] += a0 * w; acc[1][j] += a1 * w; acc[2][j] += a2 * w; acc[3][j] += a3 * w;
      }
    }
    for (int j = 0; j < 2; ++j) {
      int c = cg * 2 + j;
      float b = fc1b[c];
      for (int i = 0; i < 4; ++i) {
        float t = acc[i][j] + b;
        sH[(vg * 4 + i) * PH + c] = (t >= 0.f) ? t : 0.15f * t;
      }
    }
  }

  // ---- cube sampling + conv: 375 -> 128 (2 ch/thread) ----
  float cacc[4][2] = {{0.f, 0.f}, {0.f, 0.f}, {0.f, 0.f}, {0.f, 0.f}};
  {
    const float* vols[3] = {vol0, vol1, vol2};
    const int dims[3] = {192, 96, 48};
    const float scl[3] = {96.f, 48.f, 24.f};
    const int ups[3] = {189, 93, 45};
    for (int s = 0; s < 3; ++s) {
      __syncthreads();  // protect sCube reuse (and sIn ready on first pass)
      const float* vol = vols[s];
      const int dim = dims[s];
      const float sc = scl[s];
      const int up = ups[s];
      for (int t = tid; t < TILE_V * 125; t += BLOCK) {
        int v = t / 125;
        int j = t - v * 125;
        int dx = j / 25; int r = j - dx * 25; int dy = r / 5; int dz = r - dy * 5;
        float px = sIn[v * PIN + 0], py = sIn[v * PIN + 1], pz = sIn[v * PIN + 2];
        int ix = (int)rintf((px + 1.f) * sc);
        int iy = (int)rintf((py + 1.f) * sc);
        int iz = (int)rintf((pz + 1.f) * sc);
        ix = min(max(ix, 2), up); iy = min(max(iy, 2), up); iz = min(max(iz, 2), up);
        sCube[v * PC + j] =
            vol[(size_t)(ix + dx - 2) * dim * dim + (size_t)(iy + dy - 2) * dim + (iz + dz - 2)];
      }
      __syncthreads();
      for (int k = 0; k < 125; ++k) {
        float a0 = sCube[(vg * 4 + 0) * PC + k];
        float a1 = sCube[(vg * 4 + 1) * PC + k];
        float a2 = sCube[(vg * 4 + 2) * PC + k];
        float a3 = sCube[(vg * 4 + 3) * PC + k];
        for (int j = 0; j < 2; ++j) {
          float w = convw[(cg * 2 + j) * 375 + s * 125 + k];
          cacc[0][j] += a0 * w; cacc[1][j] += a1 * w; cacc[2][j] += a2 * w; cacc[3][j] += a3 * w;
        }
      }
    }
  }
  __syncthreads();
  for (int j = 0; j < 2; ++j) {
    float b = convb[cg * 2 + j];
    for (int i = 0; i < 4; ++i) sXl1[(vg * 4 + i) * PX + cg * 2 + j] = cacc[i][j] + b;
  }
  __syncthreads();

  // ---- lfc: 128 -> 128 (no activation), out -> sH[.][128..255] ----
  {
    float acc[4][2] = {{0.f, 0.f}, {0.f, 0.f}, {0.f, 0.f}, {0.f, 0.f}};
    for (int k0 = 0; k0 < 128; k0 += 4) {
      float a[4][4];
      for (int i = 0; i < 4; ++i)
        for (int kk = 0; kk < 4; ++kk) a[i][kk] = sXl1[(vg * 4 + i) * PX + k0 + kk];
      for (int j = 0; j < 2; ++j) {
        const float4 w = *(const float4*)&lfcw[(cg * 2 + j) * 128 + k0];
        for (int i = 0; i < 4; ++i)
          acc[i][j] += a[i][0] * w.x + a[i][1] * w.y + a[i][2] * w.z + a[i][3] * w.w;
      }
    }
    __syncthreads();
    for (int j = 0; j < 2; ++j) {
      float b = lfcb[cg * 2 + j];
      for (int i = 0; i < 4; ++i) sH[(vg * 4 + i) * PH + 128 + cg * 2 + j] = acc[i][j] + b;
    }
  }
  __syncthreads();

  // ---- fc2: 256 -> 512, lrelu, out -> sG (8 ch/thread) ----
  {
    float acc[4][8];
    for (int i = 0; i < 4; ++i) for (int j = 0; j < 8; ++j) acc[i][j] = 0.f;
    for (int k0 = 0; k0 < 256; k0 += 4) {
      float a[4][4];
      for (int i = 0; i < 4; ++i)
        for (int kk = 0; kk < 4; ++kk) a[i][kk] = sH[(vg * 4 + i) * PH + k0 + kk];
      for (int j = 0; j < 8; ++j) {
        const float4 w = *(const float4*)&fc2w[(cg * 8 + j) * 256 + k0];
        for (int i = 0; i < 4; ++i)
          acc[i][j] += a[i][0] * w.x + a[i][1] * w.y + a[i][2] * w.z + a[i][3] * w.w;
      }
    }
    for (int j = 0; j < 8; ++j) {
      int c = cg * 8 + j;
      float b = fc2b[c];
      for (int i = 0; i < 4; ++i) {
        float t = acc[i][j] + b;
        sG[(vg * 4 + i) * PG + c] = (t >= 0.f) ? t : 0.15f * t;
      }
    }
  }
  __syncthreads();

  // ---- fc3: 512 -> 256, lrelu, out -> sH (4 ch/thread) ----
  {
    float acc[4][4];
    for (int i = 0; i < 4; ++i) for (int j = 0; j < 4; ++j) acc[i][j] = 0.f;
    for (int k0 = 0; k0 < 512; k0 += 4) {
      float a[4][4];
      for (int i = 0; i < 4; ++i)
        for (int kk = 0; kk < 4; ++kk) a[i][kk] = sG[(vg * 4 + i) * PG + k0 + kk];
      for (int j = 0; j < 4; ++j) {
        const float4 w = *(const float4*)&fc3w[(cg * 4 + j) * 512 + k0];
        for (int i = 0; i < 4; ++i)
          acc[i][j] += a[i][0] * w.x + a[i][1] * w.y + a[i][2] * w.z + a[i][3] * w.w;
      }
    }
    __syncthreads();  // everyone done reading sG before sH overwrite ordering below
    for (int j = 0; j < 4; ++j) {
      int c = cg * 4 + j;
      float b = fc3b[c];
      for (int i = 0; i < 4; ++i) {
        float t = acc[i][j] + b;
        sH[(vg * 4 + i) * PH + c] = (t >= 0.f) ? t : 0.15f * t;
      }
    }
  }
  __syncthreads();

  // ---- fc4: 256 -> 3, x += 0.1*tanh ----
  if (tid < 64) {
    int v = tid >> 2, c = tid & 3;
    if (c < 3) {
      float acc = 0.f;
      for (int k = 0; k < 256; ++k) acc += sH[v * PH + k] * fc4w[c * 256 + k];
      int vid = v0 + v;
      float old = x[vid * 3 + c];
      x[vid * 3 + c] = old + 0.1f * tanhf(acc + fc4b[c]);
    }
  }
}

extern "C" void kernel_launch(void* const* d_in, const int* in_sizes, int n_in,
                              void* d_out, int out_size, void* d_ws, size_t ws_size,
                              hipStream_t stream) {
  const float* v = (const float*)d_in[0];
  const int* f = (const int*)d_in[1];
  const float* vol0 = (const float*)d_in[2];
  const float* fc1w = (const float*)d_in[3];
  const float* fc1b = (const float*)d_in[4];
  const float* fc2w = (const float*)d_in[5];
  const float* fc2b = (const float*)d_in[6];
  const float* fc3w = (const float*)d_in[7];
  const float* fc3b = (const float*)d_in[8];
  const float* fc4w = (const float*)d_in[9];
  const float* fc4b = (const float*)d_in[10];
  const float* convw = (const float*)d_in[11];
  const float* convb = (const float*)d_in[12];
  const float* lfcw = (const float*)d_in[13];
  const float* lfcb = (const float*)d_in[14];
  const int* nsm = (const int*)d_in[15];

  float* ws = (float*)d_ws;
  float* x    = ws;                 // 450000
  float* nrm  = ws + 450000;        // 450000
  float* cnt  = ws + 900000;        // 150000
  float* xs   = ws + 1050000;       // 450000
  float* vol1 = ws + 1500000;       // 884736
  float* vol2 = ws + 2384736;       // 110592

  hipMemcpyAsync(x, v, (size_t)NV * 3 * sizeof(float), hipMemcpyDeviceToDevice, stream);
  ds_kernel<<<3456, 256, 0, stream>>>(vol0, vol1, 96);
  ds_kernel<<<432, 256, 0, stream>>>(vol1, vol2, 48);
  hipMemsetAsync(cnt, 0, (size_t)NV * sizeof(float), stream);
  cnt_kernel<<<(NFACE + 255) / 256, 256, 0, stream>>>(f, cnt);

  for (int b = 0; b < 3; ++b) {
    hipMemsetAsync(nrm, 0, (size_t)NV * 3 * sizeof(float), stream);
    face_normals_kernel<<<(NFACE + 255) / 256, 256, 0, stream>>>(x, f, nrm);
    block_kernel<<<NV / TILE_V, 256, 0, stream>>>(
        x, nrm, vol0, vol1, vol2,
        fc1w + b * 128 * 6, fc1b + b * 128,
        convw + b * 128 * 375, convb + b * 128,
        lfcw + b * 128 * 128, lfcb + b * 128,
        fc2w + b * 512 * 256, fc2b + b * 512,
        fc3w + b * 256 * 512, fc3b + b * 256,
        fc4w + b * 3 * 256, fc4b + b * 3);
  }

  hipMemsetAsync(xs, 0, (size_t)NV * 3 * sizeof(float), stream);
  smooth_scatter_kernel<<<(NFACE + 255) / 256, 256, 0, stream>>>(x, f, xs);
  finalize_kernel<<<(NV * 3 + 255) / 256, 256, 0, stream>>>(xs, cnt, x, nsm, (float*)d_out);
}

// Round 7
// 5882.534 us; speedup vs baseline: 1.3620x; 1.3620x over previous
//
#include <hip/hip_runtime.h>
#include <math.h>

#define NV 150000
#define NFACE 300000
#define MV 32          // vertices per block
#define NTHR 512       // 8 waves

// LDS arena (f32 units)
#define PIN 9
#define PH2 268        // h row pitch (256 used + pad) ; 268%32=12 -> ~2-way on b128
#define PG2 524        // g row pitch (512 used + pad) ; 524%32=12
#define OFF_IN 0                   // [32][9]
#define OFF_H 288                  // [32][268]
#define OFF_G (288 + 32*268)       // [32][524]  (cols 0..383 = cubes, 384..511 = xl1, then fc2 out 0..511)
#define ARENA (288 + 32*268 + 32*524)   // 25632 f32 = 102528 B

typedef _Float16 h8v __attribute__((ext_vector_type(8)));
typedef float f4v __attribute__((ext_vector_type(4)));

// ---------------- small helper kernels ----------------

__global__ __launch_bounds__(256) void ds_kernel(const float* __restrict__ in,
                                                 float* __restrict__ out, int od) {
  int t = blockIdx.x * 256 + threadIdx.x;
  int tot = od * od * od;
  if (t >= tot) return;
  int oz = t % od; int r = t / od; int oy = r % od; int ox = r / od;
  int id = od * 2;
  size_t base = ((size_t)(2 * ox) * id + (size_t)(2 * oy)) * id + (size_t)(2 * oz);
  float s = 0.f;
  for (int i = 0; i < 2; ++i)
    for (int j = 0; j < 2; ++j)
      for (int k = 0; k < 2; ++k)
        s += in[base + (size_t)i * id * id + (size_t)j * id + k];
  out[t] = s * 0.125f;
}

__global__ __launch_bounds__(256) void face_normals_kernel(const float* __restrict__ x,
                                                           const int* __restrict__ f,
                                                           float* __restrict__ nrm) {
  int i = blockIdx.x * 256 + threadIdx.x;
  if (i >= NFACE) return;
  int a = f[i * 3 + 0], b = f[i * 3 + 1], c = f[i * 3 + 2];
  float ax = x[a * 3 + 0], ay = x[a * 3 + 1], az = x[a * 3 + 2];
  float bx = x[b * 3 + 0], by = x[b * 3 + 1], bz = x[b * 3 + 2];
  float cx = x[c * 3 + 0], cy = x[c * 3 + 1], cz = x[c * 3 + 2];
  float ux = bx - ax, uy = by - ay, uz = bz - az;
  float vx = cx - ax, vy = cy - ay, vz = cz - az;
  float nx = uy * vz - uz * vy;
  float ny = uz * vx - ux * vz;
  float nz = ux * vy - uy * vx;
  atomicAdd(&nrm[a * 3 + 0], nx); atomicAdd(&nrm[a * 3 + 1], ny); atomicAdd(&nrm[a * 3 + 2], nz);
  atomicAdd(&nrm[b * 3 + 0], nx); atomicAdd(&nrm[b * 3 + 1], ny); atomicAdd(&nrm[b * 3 + 2], nz);
  atomicAdd(&nrm[c * 3 + 0], nx); atomicAdd(&nrm[c * 3 + 1], ny); atomicAdd(&nrm[c * 3 + 2], nz);
}

__global__ __launch_bounds__(256) void cnt_kernel(const int* __restrict__ f,
                                                  float* __restrict__ cnt) {
  int i = blockIdx.x * 256 + threadIdx.x;
  if (i >= NFACE) return;
  atomicAdd(&cnt[f[i * 3 + 0]], 1.f);
  atomicAdd(&cnt[f[i * 3 + 1]], 1.f);
  atomicAdd(&cnt[f[i * 3 + 2]], 1.f);
}

__global__ __launch_bounds__(256) void smooth_scatter_kernel(const float* __restrict__ x,
                                                             const int* __restrict__ f,
                                                             float* __restrict__ xs) {
  int i = blockIdx.x * 256 + threadIdx.x;
  if (i >= NFACE) return;
  int a = f[i * 3 + 0], b = f[i * 3 + 1], c = f[i * 3 + 2];
  for (int d = 0; d < 3; ++d) atomicAdd(&xs[b * 3 + d], x[a * 3 + d]);
  for (int d = 0; d < 3; ++d) atomicAdd(&xs[c * 3 + d], x[b * 3 + d]);
  for (int d = 0; d < 3; ++d) atomicAdd(&xs[a * 3 + d], x[c * 3 + d]);
}

__global__ __launch_bounds__(256) void finalize_kernel(const float* __restrict__ xs,
                                                       const float* __restrict__ cnt,
                                                       const float* __restrict__ x,
                                                       const int* __restrict__ nsm,
                                                       float* __restrict__ out) {
  int e = blockIdx.x * 256 + threadIdx.x;
  if (e >= NV * 3) return;
  int ns = nsm[0];
  if (ns >= 1) {
    int v = e / 3;
    float c = fmaxf(cnt[v], 1.f);
    out[e] = xs[e] / c;
  } else {
    out[e] = x[e];
  }
}

// ---------------- weight prep: f32 -> f16 hi/lo planes ----------------

__global__ __launch_bounds__(256) void wprep_kernel(const float* __restrict__ src,
                                                    _Float16* __restrict__ hi,
                                                    _Float16* __restrict__ lo, int n) {
  int i = blockIdx.x * 256 + threadIdx.x;
  if (i >= n) return;
  float v = src[i];
  _Float16 h = (_Float16)v;
  hi[i] = h;
  lo[i] = (_Float16)(v - (float)h);
}

// conv weights: [3*128][375] (s*125+j) -> padded [3*128][384] (s*128+j, j>=125 zero)
__global__ __launch_bounds__(256) void wprep_conv_kernel(const float* __restrict__ src,
                                                         _Float16* __restrict__ hi,
                                                         _Float16* __restrict__ lo) {
  int i = blockIdx.x * 256 + threadIdx.x;
  const int tot = 3 * 128 * 384;
  if (i >= tot) return;
  int col = i % 384, row = i / 384;
  int s = col >> 7, j = col & 127;
  float v = (j < 125) ? src[row * 375 + s * 125 + j] : 0.f;
  _Float16 h = (_Float16)v;
  hi[i] = h;
  lo[i] = (_Float16)(v - (float)h);
}

// ---------------- fused deformation block with f16x3 MFMA GEMMs ----------------

template <int NT, int KSTEPS, int K, bool ACT>
__device__ __forceinline__ void gemm_mfma(const float* __restrict__ Alds, int astride, int m0,
                                          const _Float16* __restrict__ WH,
                                          const _Float16* __restrict__ WL,
                                          const float* __restrict__ bias, int n0base,
                                          float* __restrict__ Olds, int ostride, int lane) {
  f4v acc[NT];
#pragma unroll
  for (int t = 0; t < NT; ++t) acc[t] = (f4v){0.f, 0.f, 0.f, 0.f};
  const int r16 = lane & 15, kq = lane >> 4;
  const float* arow = Alds + (m0 + r16) * astride + kq * 8;
  const _Float16* wh = WH + (size_t)(n0base + r16) * K + kq * 8;
  const _Float16* wl = WL + (size_t)(n0base + r16) * K + kq * 8;
#pragma unroll
  for (int k0 = 0; k0 < KSTEPS; ++k0) {
    float4 aA = *(const float4*)(arow + k0 * 32);
    float4 aB = *(const float4*)(arow + k0 * 32 + 4);
    float av[8] = {aA.x, aA.y, aA.z, aA.w, aB.x, aB.y, aB.z, aB.w};
    h8v ah, al;
#pragma unroll
    for (int e = 0; e < 8; ++e) {
      _Float16 h = (_Float16)av[e];
      ah[e] = h;
      al[e] = (_Float16)(av[e] - (float)h);
    }
#pragma unroll
    for (int t = 0; t < NT; ++t) {
      const _Float16* ph = wh + (size_t)t * 16 * K + k0 * 32;
      const _Float16* pl = wl + (size_t)t * 16 * K + k0 * 32;
      h8v bh = *(const h8v*)ph;
      h8v bl = *(const h8v*)pl;
      acc[t] = __builtin_amdgcn_mfma_f32_16x16x32_f16(ah, bh, acc[t], 0, 0, 0);
      acc[t] = __builtin_amdgcn_mfma_f32_16x16x32_f16(al, bh, acc[t], 0, 0, 0);
      acc[t] = __builtin_amdgcn_mfma_f32_16x16x32_f16(ah, bl, acc[t], 0, 0, 0);
    }
  }
#pragma unroll
  for (int t = 0; t < NT; ++t) {
    int n = n0base + t * 16 + r16;
    float b = bias[n];
#pragma unroll
    for (int r = 0; r < 4; ++r) {
      int row = m0 + kq * 4 + r;
      float v = acc[t][r] + b;
      if (ACT) v = (v >= 0.f) ? v : 0.15f * v;
      Olds[row * ostride + n] = v;
    }
  }
}

__global__ __launch_bounds__(512, 1) void block_kernel(
    float* __restrict__ x, const float* __restrict__ nrm,
    const float* __restrict__ vol0, const float* __restrict__ vol1, const float* __restrict__ vol2,
    const float* __restrict__ fc1w, const float* __restrict__ fc1b,
    const _Float16* __restrict__ convH, const _Float16* __restrict__ convL,
    const float* __restrict__ convb,
    const _Float16* __restrict__ lfcH, const _Float16* __restrict__ lfcL,
    const float* __restrict__ lfcb,
    const _Float16* __restrict__ fc2H, const _Float16* __restrict__ fc2L,
    const float* __restrict__ fc2b,
    const _Float16* __restrict__ fc3H, const _Float16* __restrict__ fc3L,
    const float* __restrict__ fc3b,
    const float* __restrict__ fc4w, const float* __restrict__ fc4b) {
  __shared__ float S[ARENA];
  float* sIn = S + OFF_IN;   // [32][9]
  float* sH = S + OFF_H;     // [32][268]
  float* sG = S + OFF_G;     // [32][524]

  const int tid = threadIdx.x;
  const int v0 = blockIdx.x * MV;
  const int w = tid >> 6;    // wave 0..7
  const int lane = tid & 63;
  const int m0 = (w & 1) * 16;

  // ---- phase 0: stage inputs (clamped for the partial last tile) ----
  if (tid < MV) {
    int vid = min(v0 + tid, NV - 1);
    float px = x[vid * 3 + 0], py = x[vid * 3 + 1], pz = x[vid * 3 + 2];
    float nx = nrm[vid * 3 + 0], ny = nrm[vid * 3 + 1], nz = nrm[vid * 3 + 2];
    float nn = sqrtf(nx * nx + ny * ny + nz * nz);
    float d = fmaxf(nn, 1e-12f);
    sIn[tid * PIN + 0] = px; sIn[tid * PIN + 1] = py; sIn[tid * PIN + 2] = pz;
    sIn[tid * PIN + 3] = nx / d; sIn[tid * PIN + 4] = ny / d; sIn[tid * PIN + 5] = nz / d;
  }
  __syncthreads();

  // ---- phase 1: fc1 (f32 VALU) + cube gather (both read only sIn) ----
  {
    // fc1: 6 -> 128, lrelu -> sH cols 0..127. thread: vertex tid>>4, 8 channels.
    int v = tid >> 4;
    int c0 = (tid & 15) * 8;
    float in6[6];
#pragma unroll
    for (int k = 0; k < 6; ++k) in6[k] = sIn[v * PIN + k];
#pragma unroll
    for (int j = 0; j < 8; ++j) {
      int c = c0 + j;
      float a = fc1b[c];
#pragma unroll
      for (int k = 0; k < 6; ++k) a += in6[k] * fc1w[c * 6 + k];
      sH[v * PH2 + c] = (a >= 0.f) ? a : 0.15f * a;
    }
    // zero the conv K-pad columns (s*128+125..127)
    if (tid < 288) {
      int s = tid / 96, rem = tid % 96;
      int vz = rem / 3, jj = 125 + rem % 3;
      sG[vz * PG2 + s * 128 + jj] = 0.f;
    }
    // gather: 3 scales x 32 verts x 125 samples -> sG cols [s*128 + j]
    const float* vols[3] = {vol0, vol1, vol2};
    const int dims[3] = {192, 96, 48};
    const float scl[3] = {96.f, 48.f, 24.f};
    const int ups[3] = {189, 93, 45};
    for (int t = tid; t < 12000; t += NTHR) {
      int s = t / 4000;
      int rem = t - s * 4000;
      int v2 = rem / 125;
      int j = rem - v2 * 125;
      int dx = j / 25; int r2 = j - dx * 25; int dy = r2 / 5; int dz = r2 - dy * 5;
      float px = sIn[v2 * PIN + 0], py = sIn[v2 * PIN + 1], pz = sIn[v2 * PIN + 2];
      float sc = scl[s];
      int up = ups[s];
      int dim = dims[s];
      int ix = (int)rintf((px + 1.f) * sc);
      int iy = (int)rintf((py + 1.f) * sc);
      int iz = (int)rintf((pz + 1.f) * sc);
      ix = min(max(ix, 2), up); iy = min(max(iy, 2), up); iz = min(max(iz, 2), up);
      sG[v2 * PG2 + s * 128 + j] =
          vols[s][(size_t)(ix + dx - 2) * dim * dim + (size_t)(iy + dy - 2) * dim + (iz + dz - 2)];
    }
  }
  __syncthreads();

  // ---- phase 2: conv 384 -> 128 (MFMA), out + bias -> sG cols 384..511 ----
  gemm_mfma<2, 12, 384, false>(sG, PG2, m0, convH, convL, convb, (w >> 1) * 32,
                               sG + 384, PG2, lane);
  __syncthreads();

  // ---- phase 3: lfc 128 -> 128 (MFMA), out + bias -> sH cols 128..255 ----
  gemm_mfma<2, 4, 128, false>(sG + 384, PG2, m0, lfcH, lfcL, lfcb, (w >> 1) * 32,
                              sH + 128, PH2, lane);
  __syncthreads();

  // ---- phase 4: fc2 256 -> 512 (MFMA), lrelu -> sG cols 0..511 ----
  gemm_mfma<8, 8, 256, true>(sH, PH2, m0, fc2H, fc2L, fc2b, (w >> 1) * 128,
                             sG, PG2, lane);
  __syncthreads();

  // ---- phase 5: fc3 512 -> 256 (MFMA), lrelu -> sH cols 0..255 ----
  gemm_mfma<4, 16, 512, true>(sG, PG2, m0, fc3H, fc3L, fc3b, (w >> 1) * 64,
                              sH, PH2, lane);
  __syncthreads();

  // ---- phase 6: fc4 256 -> 3, x += 0.1*tanh ----
  if (tid < 96) {
    int v = tid / 3, c = tid % 3;
    float acc = fc4b[c];
    for (int k = 0; k < 256; ++k) acc += sH[v * PH2 + k] * fc4w[c * 256 + k];
    int vid = v0 + v;
    if (vid < NV) {
      float old = x[vid * 3 + c];
      x[vid * 3 + c] = old + 0.1f * tanhf(acc);
    }
  }
}

// ---------------- launch ----------------

extern "C" void kernel_launch(void* const* d_in, const int* in_sizes, int n_in,
                              void* d_out, int out_size, void* d_ws, size_t ws_size,
                              hipStream_t stream) {
  const float* v = (const float*)d_in[0];
  const int* f = (const int*)d_in[1];
  const float* vol0 = (const float*)d_in[2];
  const float* fc1w = (const float*)d_in[3];
  const float* fc1b = (const float*)d_in[4];
  const float* fc2w = (const float*)d_in[5];
  const float* fc2b = (const float*)d_in[6];
  const float* fc3w = (const float*)d_in[7];
  const float* fc3b = (const float*)d_in[8];
  const float* fc4w = (const float*)d_in[9];
  const float* fc4b = (const float*)d_in[10];
  const float* convw = (const float*)d_in[11];
  const float* convb = (const float*)d_in[12];
  const float* lfcw = (const float*)d_in[13];
  const float* lfcb = (const float*)d_in[14];
  const int* nsm = (const int*)d_in[15];

  float* ws = (float*)d_ws;
  float* x = ws;                  // 450000
  float* nrm = ws + 450000;       // 450000
  float* cnt = ws + 900000;       // 150000
  float* xs = ws + 1050000;       // 450000
  float* vol1 = ws + 1500000;     // 884736
  float* vol2 = ws + 2384736;     // 110592
  _Float16* w16 = (_Float16*)(ws + 2495328);
  _Float16* convH = w16;                 // 3*128*384 = 147456
  _Float16* convL = w16 + 147456;
  _Float16* lfcH = w16 + 294912;         // 3*16384
  _Float16* lfcL = w16 + 344064;
  _Float16* fc2H = w16 + 393216;         // 3*131072
  _Float16* fc2L = w16 + 786432;
  _Float16* fc3H = w16 + 1179648;        // 3*131072
  _Float16* fc3L = w16 + 1572864;

  hipMemcpyAsync(x, v, (size_t)NV * 3 * sizeof(float), hipMemcpyDeviceToDevice, stream);
  ds_kernel<<<3456, 256, 0, stream>>>(vol0, vol1, 96);
  ds_kernel<<<432, 256, 0, stream>>>(vol1, vol2, 48);
  hipMemsetAsync(cnt, 0, (size_t)NV * sizeof(float), stream);
  cnt_kernel<<<(NFACE + 255) / 256, 256, 0, stream>>>(f, cnt);

  // weight prep (hi/lo split), all 3 blocks at once
  wprep_conv_kernel<<<(3 * 128 * 384 + 255) / 256, 256, 0, stream>>>(convw, convH, convL);
  wprep_kernel<<<(3 * 16384 + 255) / 256, 256, 0, stream>>>(lfcw, lfcH, lfcL, 3 * 16384);
  wprep_kernel<<<(3 * 131072 + 255) / 256, 256, 0, stream>>>(fc2w, fc2H, fc2L, 3 * 131072);
  wprep_kernel<<<(3 * 131072 + 255) / 256, 256, 0, stream>>>(fc3w, fc3H, fc3L, 3 * 131072);

  const int nblk = (NV + MV - 1) / MV;  // 4688
  for (int b = 0; b < 3; ++b) {
    hipMemsetAsync(nrm, 0, (size_t)NV * 3 * sizeof(float), stream);
    face_normals_kernel<<<(NFACE + 255) / 256, 256, 0, stream>>>(x, f, nrm);
    block_kernel<<<nblk, NTHR, 0, stream>>>(
        x, nrm, vol0, vol1, vol2,
        fc1w + b * 128 * 6, fc1b + b * 128,
        convH + b * 49152, convL + b * 49152, convb + b * 128,
        lfcH + b * 16384, lfcL + b * 16384, lfcb + b * 128,
        fc2H + b * 131072, fc2L + b * 131072, fc2b + b * 512,
        fc3H + b * 131072, fc3L + b * 131072, fc3b + b * 256,
        fc4w + b * 768, fc4b + b * 3);
  }

  hipMemsetAsync(xs, 0, (size_t)NV * 3 * sizeof(float), stream);
  smooth_scatter_kernel<<<(NFACE + 255) / 256, 256, 0, stream>>>(x, f, xs);
  finalize_kernel<<<(NV * 3 + 255) / 256, 256, 0, stream>>>(xs, cnt, x, nsm, (float*)d_out);
}

// Round 11
// 5079.849 us; speedup vs baseline: 1.5772x; 1.1580x over previous
//
#include <hip/hip_runtime.h>
#include <math.h>

#define NV 150000
#define NFACE 300000
#define MV 16          // vertices per block
#define NTHR 256       // 4 waves

// LDS arena (f32 units)
#define PIN 9
#define PH2 268        // h row pitch (256 used + pad)
#define PG2 524        // g row pitch (512 used + pad)
#define OFF_IN 0                   // [16][9]
#define OFF_H 144                  // [16][268]
#define OFF_G (144 + 16*268)       // [16][524]  (cols 0..383 cubes, 384..511 xl1, then fc2 out)
#define ARENA (144 + 16*268 + 16*524)   // 12816 f32 = 51264 B -> 3 wg/CU

typedef _Float16 h8v __attribute__((ext_vector_type(8)));
typedef float f4v __attribute__((ext_vector_type(4)));

// ---------------- small helper kernels ----------------

__global__ __launch_bounds__(256) void ds_kernel(const float* __restrict__ in,
                                                 float* __restrict__ out, int od) {
  int t = blockIdx.x * 256 + threadIdx.x;
  int tot = od * od * od;
  if (t >= tot) return;
  int oz = t % od; int r = t / od; int oy = r % od; int ox = r / od;
  int id = od * 2;
  size_t base = ((size_t)(2 * ox) * id + (size_t)(2 * oy)) * id + (size_t)(2 * oz);
  float s = 0.f;
  for (int i = 0; i < 2; ++i)
    for (int j = 0; j < 2; ++j)
      for (int k = 0; k < 2; ++k)
        s += in[base + (size_t)i * id * id + (size_t)j * id + k];
  out[t] = s * 0.125f;
}

__global__ __launch_bounds__(256) void face_normals_kernel(const float* __restrict__ x,
                                                           const int* __restrict__ f,
                                                           float* __restrict__ nrm) {
  int i = blockIdx.x * 256 + threadIdx.x;
  if (i >= NFACE) return;
  int a = f[i * 3 + 0], b = f[i * 3 + 1], c = f[i * 3 + 2];
  float ax = x[a * 3 + 0], ay = x[a * 3 + 1], az = x[a * 3 + 2];
  float bx = x[b * 3 + 0], by = x[b * 3 + 1], bz = x[b * 3 + 2];
  float cx = x[c * 3 + 0], cy = x[c * 3 + 1], cz = x[c * 3 + 2];
  float ux = bx - ax, uy = by - ay, uz = bz - az;
  float vx = cx - ax, vy = cy - ay, vz = cz - az;
  float nx = uy * vz - uz * vy;
  float ny = uz * vx - ux * vz;
  float nz = ux * vy - uy * vx;
  atomicAdd(&nrm[a * 3 + 0], nx); atomicAdd(&nrm[a * 3 + 1], ny); atomicAdd(&nrm[a * 3 + 2], nz);
  atomicAdd(&nrm[b * 3 + 0], nx); atomicAdd(&nrm[b * 3 + 1], ny); atomicAdd(&nrm[b * 3 + 2], nz);
  atomicAdd(&nrm[c * 3 + 0], nx); atomicAdd(&nrm[c * 3 + 1], ny); atomicAdd(&nrm[c * 3 + 2], nz);
}

__global__ __launch_bounds__(256) void cnt_kernel(const int* __restrict__ f,
                                                  float* __restrict__ cnt) {
  int i = blockIdx.x * 256 + threadIdx.x;
  if (i >= NFACE) return;
  atomicAdd(&cnt[f[i * 3 + 0]], 1.f);
  atomicAdd(&cnt[f[i * 3 + 1]], 1.f);
  atomicAdd(&cnt[f[i * 3 + 2]], 1.f);
}

__global__ __launch_bounds__(256) void smooth_scatter_kernel(const float* __restrict__ x,
                                                             const int* __restrict__ f,
                                                             float* __restrict__ xs) {
  int i = blockIdx.x * 256 + threadIdx.x;
  if (i >= NFACE) return;
  int a = f[i * 3 + 0], b = f[i * 3 + 1], c = f[i * 3 + 2];
  for (int d = 0; d < 3; ++d) atomicAdd(&xs[b * 3 + d], x[a * 3 + d]);
  for (int d = 0; d < 3; ++d) atomicAdd(&xs[c * 3 + d], x[b * 3 + d]);
  for (int d = 0; d < 3; ++d) atomicAdd(&xs[a * 3 + d], x[c * 3 + d]);
}

__global__ __launch_bounds__(256) void finalize_kernel(const float* __restrict__ xs,
                                                       const float* __restrict__ cnt,
                                                       const float* __restrict__ x,
                                                       const int* __restrict__ nsm,
                                                       float* __restrict__ out) {
  int e = blockIdx.x * 256 + threadIdx.x;
  if (e >= NV * 3) return;
  int ns = nsm[0];
  if (ns >= 1) {
    int v = e / 3;
    float c = fmaxf(cnt[v], 1.f);
    out[e] = xs[e] / c;
  } else {
    out[e] = x[e];
  }
}

// ---------------- weight prep: f32 -> f16 hi/lo planes ----------------

__global__ __launch_bounds__(256) void wprep_kernel(const float* __restrict__ src,
                                                    _Float16* __restrict__ hi,
                                                    _Float16* __restrict__ lo, int n) {
  int i = blockIdx.x * 256 + threadIdx.x;
  if (i >= n) return;
  float v = src[i];
  _Float16 h = (_Float16)v;
  hi[i] = h;
  lo[i] = (_Float16)(v - (float)h);
}

// conv weights: [3*128][375] (s*125+j) -> padded [3*128][384] (s*128+j, j>=125 zero)
__global__ __launch_bounds__(256) void wprep_conv_kernel(const float* __restrict__ src,
                                                         _Float16* __restrict__ hi,
                                                         _Float16* __restrict__ lo) {
  int i = blockIdx.x * 256 + threadIdx.x;
  const int tot = 3 * 128 * 384;
  if (i >= tot) return;
  int col = i % 384, row = i / 384;
  int s = col >> 7, j = col & 127;
  float v = (j < 125) ? src[row * 375 + s * 125 + j] : 0.f;
  _Float16 h = (_Float16)v;
  hi[i] = h;
  lo[i] = (_Float16)(v - (float)h);
}

// ---------------- fused deformation block with f16x3 MFMA GEMMs ----------------
// M=16 rows; each wave owns an N-quadrant (NT 16-col tiles), all 16 rows.

template <int NT, int KSTEPS, int K, bool ACT>
__device__ __forceinline__ void gemm_mfma(const float* __restrict__ Alds, int astride,
                                          const _Float16* __restrict__ WH,
                                          const _Float16* __restrict__ WL,
                                          const float* __restrict__ bias, int n0base,
                                          float* __restrict__ Olds, int ostride, int lane) {
  f4v acc[NT];
#pragma unroll
  for (int t = 0; t < NT; ++t) acc[t] = (f4v){0.f, 0.f, 0.f, 0.f};
  const int r16 = lane & 15, kq = lane >> 4;
  const float* arow = Alds + r16 * astride + kq * 8;
  const _Float16* wh = WH + (size_t)(n0base + r16) * K + kq * 8;
  const _Float16* wl = WL + (size_t)(n0base + r16) * K + kq * 8;
#pragma unroll
  for (int k0 = 0; k0 < KSTEPS; ++k0) {
    float4 aA = *(const float4*)(arow + k0 * 32);
    float4 aB = *(const float4*)(arow + k0 * 32 + 4);
    float av[8] = {aA.x, aA.y, aA.z, aA.w, aB.x, aB.y, aB.z, aB.w};
    h8v ah, al;
#pragma unroll
    for (int e = 0; e < 8; ++e) {
      _Float16 h = (_Float16)av[e];
      ah[e] = h;
      al[e] = (_Float16)(av[e] - (float)h);
    }
#pragma unroll
    for (int t = 0; t < NT; ++t) {
      const _Float16* ph = wh + (size_t)t * 16 * K + k0 * 32;
      const _Float16* pl = wl + (size_t)t * 16 * K + k0 * 32;
      h8v bh = *(const h8v*)ph;
      h8v bl = *(const h8v*)pl;
      acc[t] = __builtin_amdgcn_mfma_f32_16x16x32_f16(ah, bh, acc[t], 0, 0, 0);
      acc[t] = __builtin_amdgcn_mfma_f32_16x16x32_f16(al, bh, acc[t], 0, 0, 0);
      acc[t] = __builtin_amdgcn_mfma_f32_16x16x32_f16(ah, bl, acc[t], 0, 0, 0);
    }
  }
#pragma unroll
  for (int t = 0; t < NT; ++t) {
    int n = n0base + t * 16 + r16;
    float b = bias[n];
#pragma unroll
    for (int r = 0; r < 4; ++r) {
      int row = kq * 4 + r;
      float v = acc[t][r] + b;
      if (ACT) v = (v >= 0.f) ? v : 0.15f * v;
      Olds[row * ostride + n] = v;
    }
  }
}

__global__ __launch_bounds__(256, 3) void block_kernel(
    float* __restrict__ x, const float* __restrict__ nrm,
    const float* __restrict__ vol0, const float* __restrict__ vol1, const float* __restrict__ vol2,
    const float* __restrict__ fc1w, const float* __restrict__ fc1b,
    const _Float16* __restrict__ convH, const _Float16* __restrict__ convL,
    const float* __restrict__ convb,
    const _Float16* __restrict__ lfcH, const _Float16* __restrict__ lfcL,
    const float* __restrict__ lfcb,
    const _Float16* __restrict__ fc2H, const _Float16* __restrict__ fc2L,
    const float* __restrict__ fc2b,
    const _Float16* __restrict__ fc3H, const _Float16* __restrict__ fc3L,
    const float* __restrict__ fc3b,
    const float* __restrict__ fc4w, const float* __restrict__ fc4b) {
  __shared__ float S[ARENA];
  float* sIn = S + OFF_IN;   // [16][9]
  float* sH = S + OFF_H;     // [16][268]
  float* sG = S + OFF_G;     // [16][524]

  const int tid = threadIdx.x;
  const int v0 = blockIdx.x * MV;
  const int w = tid >> 6;    // wave 0..3 -> N-quadrant
  const int lane = tid & 63;

  // ---- phase 0: stage inputs (clamped for the partial last tile) ----
  if (tid < MV) {
    int vid = min(v0 + tid, NV - 1);
    float px = x[vid * 3 + 0], py = x[vid * 3 + 1], pz = x[vid * 3 + 2];
    float nx = nrm[vid * 3 + 0], ny = nrm[vid * 3 + 1], nz = nrm[vid * 3 + 2];
    float nn = sqrtf(nx * nx + ny * ny + nz * nz);
    float d = fmaxf(nn, 1e-12f);
    sIn[tid * PIN + 0] = px; sIn[tid * PIN + 1] = py; sIn[tid * PIN + 2] = pz;
    sIn[tid * PIN + 3] = nx / d; sIn[tid * PIN + 4] = ny / d; sIn[tid * PIN + 5] = nz / d;
  }
  __syncthreads();

  // ---- phase 1: fc1 (f32 VALU) + cube gather (both read only sIn) ----
  {
    // fc1: 6 -> 128, lrelu -> sH cols 0..127. thread: vertex tid>>4, 8 channels.
    int v = tid >> 4;          // 0..15
    int c0 = (tid & 15) * 8;   // 0..120
    float in6[6];
#pragma unroll
    for (int k = 0; k < 6; ++k) in6[k] = sIn[v * PIN + k];
#pragma unroll
    for (int j = 0; j < 8; ++j) {
      int c = c0 + j;
      float a = fc1b[c];
#pragma unroll
      for (int k = 0; k < 6; ++k) a += in6[k] * fc1w[c * 6 + k];
      sH[v * PH2 + c] = (a >= 0.f) ? a : 0.15f * a;
    }
    // zero the conv K-pad columns (s*128+125..127): 3 scales x 16 verts x 3 cols = 144
    if (tid < 144) {
      int s = tid / 48, rem = tid % 48;
      int vz = rem / 3, jj = 125 + rem % 3;
      sG[vz * PG2 + s * 128 + jj] = 0.f;
    }
    // gather: 3 scales x 16 verts x 125 samples -> sG cols [s*128 + j]
    const float* vols[3] = {vol0, vol1, vol2};
    const int dims[3] = {192, 96, 48};
    const float scl[3] = {96.f, 48.f, 24.f};
    const int ups[3] = {189, 93, 45};
    for (int t = tid; t < 6000; t += NTHR) {
      int s = t / 2000;
      int rem = t - s * 2000;
      int v2 = rem / 125;
      int j = rem - v2 * 125;
      int dx = j / 25; int r2 = j - dx * 25; int dy = r2 / 5; int dz = r2 - dy * 5;
      float px = sIn[v2 * PIN + 0], py = sIn[v2 * PIN + 1], pz = sIn[v2 * PIN + 2];
      float sc = scl[s];
      int up = ups[s];
      int dim = dims[s];
      int ix = (int)rintf((px + 1.f) * sc);
      int iy = (int)rintf((py + 1.f) * sc);
      int iz = (int)rintf((pz + 1.f) * sc);
      ix = min(max(ix, 2), up); iy = min(max(iy, 2), up); iz = min(max(iz, 2), up);
      sG[v2 * PG2 + s * 128 + j] =
          vols[s][(size_t)(ix + dx - 2) * dim * dim + (size_t)(iy + dy - 2) * dim + (iz + dz - 2)];
    }
  }
  __syncthreads();

  // ---- phase 2: conv 384 -> 128 (MFMA), out + bias -> sG cols 384..511 ----
  gemm_mfma<2, 12, 384, false>(sG, PG2, convH, convL, convb, w * 32,
                               sG + 384, PG2, lane);
  __syncthreads();

  // ---- phase 3: lfc 128 -> 128 (MFMA), out + bias -> sH cols 128..255 ----
  gemm_mfma<2, 4, 128, false>(sG + 384, PG2, lfcH, lfcL, lfcb, w * 32,
                              sH + 128, PH2, lane);
  __syncthreads();

  // ---- phase 4: fc2 256 -> 512 (MFMA), lrelu -> sG cols 0..511 ----
  gemm_mfma<8, 8, 256, true>(sH, PH2, fc2H, fc2L, fc2b, w * 128,
                             sG, PG2, lane);
  __syncthreads();

  // ---- phase 5: fc3 512 -> 256 (MFMA), lrelu -> sH cols 0..255 ----
  gemm_mfma<4, 16, 512, true>(sG, PG2, fc3H, fc3L, fc3b, w * 64,
                              sH, PH2, lane);
  __syncthreads();

  // ---- phase 6: fc4 256 -> 3, x += 0.1*tanh ----
  if (tid < 48) {
    int v = tid / 3, c = tid % 3;
    float acc = fc4b[c];
    for (int k = 0; k < 256; ++k) acc += sH[v * PH2 + k] * fc4w[c * 256 + k];
    int vid = v0 + v;
    if (vid < NV) {
      float old = x[vid * 3 + c];
      x[vid * 3 + c] = old + 0.1f * tanhf(acc);
    }
  }
}

// ---------------- launch ----------------

extern "C" void kernel_launch(void* const* d_in, const int* in_sizes, int n_in,
                              void* d_out, int out_size, void* d_ws, size_t ws_size,
                              hipStream_t stream) {
  const float* v = (const float*)d_in[0];
  const int* f = (const int*)d_in[1];
  const float* vol0 = (const float*)d_in[2];
  const float* fc1w = (const float*)d_in[3];
  const float* fc1b = (const float*)d_in[4];
  const float* fc2w = (const float*)d_in[5];
  const float* fc2b = (const float*)d_in[6];
  const float* fc3w = (const float*)d_in[7];
  const float* fc3b = (const float*)d_in[8];
  const float* fc4w = (const float*)d_in[9];
  const float* fc4b = (const float*)d_in[10];
  const float* convw = (const float*)d_in[11];
  const float* convb = (const float*)d_in[12];
  const float* lfcw = (const float*)d_in[13];
  const float* lfcb = (const float*)d_in[14];
  const int* nsm = (const int*)d_in[15];

  float* ws = (float*)d_ws;
  float* x = ws;                  // 450000
  float* nrm = ws + 450000;       // 450000
  float* cnt = ws + 900000;       // 150000
  float* xs = ws + 1050000;       // 450000
  float* vol1 = ws + 1500000;     // 884736
  float* vol2 = ws + 2384736;     // 110592
  _Float16* w16 = (_Float16*)(ws + 2495328);
  _Float16* convH = w16;                 // 3*128*384 = 147456
  _Float16* convL = w16 + 147456;
  _Float16* lfcH = w16 + 294912;         // 3*16384
  _Float16* lfcL = w16 + 344064;
  _Float16* fc2H = w16 + 393216;         // 3*131072
  _Float16* fc2L = w16 + 786432;
  _Float16* fc3H = w16 + 1179648;        // 3*131072
  _Float16* fc3L = w16 + 1572864;

  hipMemcpyAsync(x, v, (size_t)NV * 3 * sizeof(float), hipMemcpyDeviceToDevice, stream);
  ds_kernel<<<3456, 256, 0, stream>>>(vol0, vol1, 96);
  ds_kernel<<<432, 256, 0, stream>>>(vol1, vol2, 48);
  hipMemsetAsync(cnt, 0, (size_t)NV * sizeof(float), stream);
  cnt_kernel<<<(NFACE + 255) / 256, 256, 0, stream>>>(f, cnt);

  // weight prep (hi/lo split), all 3 blocks at once
  wprep_conv_kernel<<<(3 * 128 * 384 + 255) / 256, 256, 0, stream>>>(convw, convH, convL);
  wprep_kernel<<<(3 * 16384 + 255) / 256, 256, 0, stream>>>(lfcw, lfcH, lfcL, 3 * 16384);
  wprep_kernel<<<(3 * 131072 + 255) / 256, 256, 0, stream>>>(fc2w, fc2H, fc2L, 3 * 131072);
  wprep_kernel<<<(3 * 131072 + 255) / 256, 256, 0, stream>>>(fc3w, fc3H, fc3L, 3 * 131072);

  const int nblk = (NV + MV - 1) / MV;  // 9375
  for (int b = 0; b < 3; ++b) {
    hipMemsetAsync(nrm, 0, (size_t)NV * 3 * sizeof(float), stream);
    face_normals_kernel<<<(NFACE + 255) / 256, 256, 0, stream>>>(x, f, nrm);
    block_kernel<<<nblk, NTHR, 0, stream>>>(
        x, nrm, vol0, vol1, vol2,
        fc1w + b * 128 * 6, fc1b + b * 128,
        convH + b * 49152, convL + b * 49152, convb + b * 128,
        lfcH + b * 16384, lfcL + b * 16384, lfcb + b * 128,
        fc2H + b * 131072, fc2L + b * 131072, fc2b + b * 512,
        fc3H + b * 131072, fc3L + b * 131072, fc3b + b * 256,
        fc4w + b * 768, fc4b + b * 3);
  }

  hipMemsetAsync(xs, 0, (size_t)NV * 3 * sizeof(float), stream);
  smooth_scatter_kernel<<<(NFACE + 255) / 256, 256, 0, stream>>>(x, f, xs);
  finalize_kernel<<<(NV * 3 + 255) / 256, 256, 0, stream>>>(xs, cnt, x, nsm, (float*)d_out);
}

// Round 13
// 5074.051 us; speedup vs baseline: 1.5791x; 1.0011x over previous
//
#include <hip/hip_runtime.h>
#include <math.h>

#define NV 150000
#define NFACE 300000
#define MV 16          // vertices per block
#define NTHR 256       // 4 waves

// LDS arena (f32 units)
#define PIN 9
#define PH2 268        // h row pitch (256 used + pad)
#define PG2 524        // g row pitch (512 used + pad)
#define OFF_IN 0                   // [16][9]
#define OFF_H 144                  // [16][268]
#define OFF_G (144 + 16*268)       // [16][524]  (cols 0..383 cubes, 384..511 xl1, then fc2 out)
#define ARENA (144 + 16*268 + 16*524)   // 12816 f32 = 51264 B -> 3 wg/CU

typedef _Float16 h8v __attribute__((ext_vector_type(8)));
typedef float f4v __attribute__((ext_vector_type(4)));

// ---------------- small helper kernels ----------------

__global__ __launch_bounds__(256) void ds_kernel(const float* __restrict__ in,
                                                 float* __restrict__ out, int od) {
  int t = blockIdx.x * 256 + threadIdx.x;
  int tot = od * od * od;
  if (t >= tot) return;
  int oz = t % od; int r = t / od; int oy = r % od; int ox = r / od;
  int id = od * 2;
  size_t base = ((size_t)(2 * ox) * id + (size_t)(2 * oy)) * id + (size_t)(2 * oz);
  float s = 0.f;
  for (int i = 0; i < 2; ++i)
    for (int j = 0; j < 2; ++j)
      for (int k = 0; k < 2; ++k)
        s += in[base + (size_t)i * id * id + (size_t)j * id + k];
  out[t] = s * 0.125f;
}

__global__ __launch_bounds__(256) void face_normals_kernel(const float* __restrict__ x,
                                                           const int* __restrict__ f,
                                                           float* __restrict__ nrm) {
  int i = blockIdx.x * 256 + threadIdx.x;
  if (i >= NFACE) return;
  int a = f[i * 3 + 0], b = f[i * 3 + 1], c = f[i * 3 + 2];
  float ax = x[a * 3 + 0], ay = x[a * 3 + 1], az = x[a * 3 + 2];
  float bx = x[b * 3 + 0], by = x[b * 3 + 1], bz = x[b * 3 + 2];
  float cx = x[c * 3 + 0], cy = x[c * 3 + 1], cz = x[c * 3 + 2];
  float ux = bx - ax, uy = by - ay, uz = bz - az;
  float vx = cx - ax, vy = cy - ay, vz = cz - az;
  float nx = uy * vz - uz * vy;
  float ny = uz * vx - ux * vz;
  float nz = ux * vy - uy * vx;
  atomicAdd(&nrm[a * 3 + 0], nx); atomicAdd(&nrm[a * 3 + 1], ny); atomicAdd(&nrm[a * 3 + 2], nz);
  atomicAdd(&nrm[b * 3 + 0], nx); atomicAdd(&nrm[b * 3 + 1], ny); atomicAdd(&nrm[b * 3 + 2], nz);
  atomicAdd(&nrm[c * 3 + 0], nx); atomicAdd(&nrm[c * 3 + 1], ny); atomicAdd(&nrm[c * 3 + 2], nz);
}

__global__ __launch_bounds__(256) void cnt_kernel(const int* __restrict__ f,
                                                  float* __restrict__ cnt) {
  int i = blockIdx.x * 256 + threadIdx.x;
  if (i >= NFACE) return;
  atomicAdd(&cnt[f[i * 3 + 0]], 1.f);
  atomicAdd(&cnt[f[i * 3 + 1]], 1.f);
  atomicAdd(&cnt[f[i * 3 + 2]], 1.f);
}

__global__ __launch_bounds__(256) void smooth_scatter_kernel(const float* __restrict__ x,
                                                             const int* __restrict__ f,
                                                             float* __restrict__ xs) {
  int i = blockIdx.x * 256 + threadIdx.x;
  if (i >= NFACE) return;
  int a = f[i * 3 + 0], b = f[i * 3 + 1], c = f[i * 3 + 2];
  for (int d = 0; d < 3; ++d) atomicAdd(&xs[b * 3 + d], x[a * 3 + d]);
  for (int d = 0; d < 3; ++d) atomicAdd(&xs[c * 3 + d], x[b * 3 + d]);
  for (int d = 0; d < 3; ++d) atomicAdd(&xs[a * 3 + d], x[c * 3 + d]);
}

__global__ __launch_bounds__(256) void finalize_kernel(const float* __restrict__ xs,
                                                       const float* __restrict__ cnt,
                                                       const float* __restrict__ x,
                                                       const int* __restrict__ nsm,
                                                       float* __restrict__ out) {
  int e = blockIdx.x * 256 + threadIdx.x;
  if (e >= NV * 3) return;
  int ns = nsm[0];
  if (ns >= 1) {
    int v = e / 3;
    float c = fmaxf(cnt[v], 1.f);
    out[e] = xs[e] / c;
  } else {
    out[e] = x[e];
  }
}

// ---------------- weight prep: f32 -> f16 hi/lo planes ----------------

__global__ __launch_bounds__(256) void wprep_kernel(const float* __restrict__ src,
                                                    _Float16* __restrict__ hi,
                                                    _Float16* __restrict__ lo, int n) {
  int i = blockIdx.x * 256 + threadIdx.x;
  if (i >= n) return;
  float v = src[i];
  _Float16 h = (_Float16)v;
  hi[i] = h;
  lo[i] = (_Float16)(v - (float)h);
}

// conv weights: [3*128][375] (s*125+j) -> padded [3*128][384] (s*128+j, j>=125 zero)
__global__ __launch_bounds__(256) void wprep_conv_kernel(const float* __restrict__ src,
                                                         _Float16* __restrict__ hi,
                                                         _Float16* __restrict__ lo) {
  int i = blockIdx.x * 256 + threadIdx.x;
  const int tot = 3 * 128 * 384;
  if (i >= tot) return;
  int col = i % 384, row = i / 384;
  int s = col >> 7, j = col & 127;
  float v = (j < 125) ? src[row * 375 + s * 125 + j] : 0.f;
  _Float16 h = (_Float16)v;
  hi[i] = h;
  lo[i] = (_Float16)(v - (float)h);
}

// ---------------- fused deformation block with f16x3 MFMA GEMMs ----------------
// M=16 rows; each wave owns NT 16-col tiles at n0base, all 16 rows.
// Register double-buffered: prefetch k0+1's A (LDS) and B (L2) before MFMAs of k0.

template <int NT, int KSTEPS, int K, bool ACT>
__device__ __forceinline__ void gemm_mfma(const float* __restrict__ Alds, int astride,
                                          const _Float16* __restrict__ WH,
                                          const _Float16* __restrict__ WL,
                                          const float* __restrict__ bias, int n0base,
                                          float* __restrict__ Olds, int ostride, int lane) {
  f4v acc[NT];
#pragma unroll
  for (int t = 0; t < NT; ++t) acc[t] = (f4v){0.f, 0.f, 0.f, 0.f};
  const int r16 = lane & 15, kq = lane >> 4;
  const float* arow = Alds + r16 * astride + kq * 8;
  const _Float16* wh = WH + (size_t)(n0base + r16) * K + kq * 8;
  const _Float16* wl = WL + (size_t)(n0base + r16) * K + kq * 8;

  // prologue: fetch k0 = 0
  float4 aA = *(const float4*)(arow);
  float4 aB = *(const float4*)(arow + 4);
  h8v bh[NT], bl[NT];
#pragma unroll
  for (int t = 0; t < NT; ++t) {
    bh[t] = *(const h8v*)(wh + (size_t)t * 16 * K);
    bl[t] = *(const h8v*)(wl + (size_t)t * 16 * K);
  }

#pragma unroll
  for (int k0 = 0; k0 < KSTEPS; ++k0) {
    // prefetch k0+1 while MFMAs of k0 run below
    float4 aA2, aB2;
    h8v bh2[NT], bl2[NT];
    if (k0 + 1 < KSTEPS) {
      aA2 = *(const float4*)(arow + (k0 + 1) * 32);
      aB2 = *(const float4*)(arow + (k0 + 1) * 32 + 4);
#pragma unroll
      for (int t = 0; t < NT; ++t) {
        bh2[t] = *(const h8v*)(wh + (size_t)t * 16 * K + (k0 + 1) * 32);
        bl2[t] = *(const h8v*)(wl + (size_t)t * 16 * K + (k0 + 1) * 32);
      }
    }
    // convert current A to hi/lo f16
    float av[8] = {aA.x, aA.y, aA.z, aA.w, aB.x, aB.y, aB.z, aB.w};
    h8v ah, al;
#pragma unroll
    for (int e = 0; e < 8; ++e) {
      _Float16 h = (_Float16)av[e];
      ah[e] = h;
      al[e] = (_Float16)(av[e] - (float)h);
    }
#pragma unroll
    for (int t = 0; t < NT; ++t) {
      acc[t] = __builtin_amdgcn_mfma_f32_16x16x32_f16(ah, bh[t], acc[t], 0, 0, 0);
      acc[t] = __builtin_amdgcn_mfma_f32_16x16x32_f16(al, bh[t], acc[t], 0, 0, 0);
      acc[t] = __builtin_amdgcn_mfma_f32_16x16x32_f16(ah, bl[t], acc[t], 0, 0, 0);
    }
    if (k0 + 1 < KSTEPS) {
      aA = aA2; aB = aB2;
#pragma unroll
      for (int t = 0; t < NT; ++t) { bh[t] = bh2[t]; bl[t] = bl2[t]; }
    }
  }
#pragma unroll
  for (int t = 0; t < NT; ++t) {
    int n = n0base + t * 16 + r16;
    float b = bias[n];
#pragma unroll
    for (int r = 0; r < 4; ++r) {
      int row = kq * 4 + r;
      float v = acc[t][r] + b;
      if (ACT) v = (v >= 0.f) ? v : 0.15f * v;
      Olds[row * ostride + n] = v;
    }
  }
}

__global__ __launch_bounds__(256, 3) void block_kernel(
    float* __restrict__ x, const float* __restrict__ nrm,
    const float* __restrict__ vol0, const float* __restrict__ vol1, const float* __restrict__ vol2,
    const float* __restrict__ fc1w, const float* __restrict__ fc1b,
    const _Float16* __restrict__ convH, const _Float16* __restrict__ convL,
    const float* __restrict__ convb,
    const _Float16* __restrict__ lfcH, const _Float16* __restrict__ lfcL,
    const float* __restrict__ lfcb,
    const _Float16* __restrict__ fc2H, const _Float16* __restrict__ fc2L,
    const float* __restrict__ fc2b,
    const _Float16* __restrict__ fc3H, const _Float16* __restrict__ fc3L,
    const float* __restrict__ fc3b,
    const float* __restrict__ fc4w, const float* __restrict__ fc4b) {
  __shared__ float S[ARENA];
  float* sIn = S + OFF_IN;   // [16][9]
  float* sH = S + OFF_H;     // [16][268]
  float* sG = S + OFF_G;     // [16][524]

  const int tid = threadIdx.x;
  const int v0 = blockIdx.x * MV;
  const int w = tid >> 6;    // wave 0..3 -> N-quadrant
  const int lane = tid & 63;

  // ---- phase 0: stage inputs (clamped for the partial last tile) ----
  if (tid < MV) {
    int vid = min(v0 + tid, NV - 1);
    float px = x[vid * 3 + 0], py = x[vid * 3 + 1], pz = x[vid * 3 + 2];
    float nx = nrm[vid * 3 + 0], ny = nrm[vid * 3 + 1], nz = nrm[vid * 3 + 2];
    float nn = sqrtf(nx * nx + ny * ny + nz * nz);
    float d = fmaxf(nn, 1e-12f);
    sIn[tid * PIN + 0] = px; sIn[tid * PIN + 1] = py; sIn[tid * PIN + 2] = pz;
    sIn[tid * PIN + 3] = nx / d; sIn[tid * PIN + 4] = ny / d; sIn[tid * PIN + 5] = nz / d;
  }
  __syncthreads();

  // ---- phase 1: fc1 (f32 VALU) + cube gather (both read only sIn) ----
  {
    // fc1: 6 -> 128, lrelu -> sH cols 0..127. thread: vertex tid>>4, 8 channels.
    int v = tid >> 4;          // 0..15
    int c0 = (tid & 15) * 8;   // 0..120
    float in6[6];
#pragma unroll
    for (int k = 0; k < 6; ++k) in6[k] = sIn[v * PIN + k];
#pragma unroll
    for (int j = 0; j < 8; ++j) {
      int c = c0 + j;
      float a = fc1b[c];
#pragma unroll
      for (int k = 0; k < 6; ++k) a += in6[k] * fc1w[c * 6 + k];
      sH[v * PH2 + c] = (a >= 0.f) ? a : 0.15f * a;
    }
    // zero the conv K-pad columns (s*128+125..127): 3 scales x 16 verts x 3 cols = 144
    if (tid < 144) {
      int s = tid / 48, rem = tid % 48;
      int vz = rem / 3, jj = 125 + rem % 3;
      sG[vz * PG2 + s * 128 + jj] = 0.f;
    }
    // gather: 3 scales x 16 verts x 125 samples -> sG cols [s*128 + j]
    const float* vols[3] = {vol0, vol1, vol2};
    const int dims[3] = {192, 96, 48};
    const float scl[3] = {96.f, 48.f, 24.f};
    const int ups[3] = {189, 93, 45};
    for (int t = tid; t < 6000; t += NTHR) {
      int s = t / 2000;
      int rem = t - s * 2000;
      int v2 = rem / 125;
      int j = rem - v2 * 125;
      int dx = j / 25; int r2 = j - dx * 25; int dy = r2 / 5; int dz = r2 - dy * 5;
      float px = sIn[v2 * PIN + 0], py = sIn[v2 * PIN + 1], pz = sIn[v2 * PIN + 2];
      float sc = scl[s];
      int up = ups[s];
      int dim = dims[s];
      int ix = (int)rintf((px + 1.f) * sc);
      int iy = (int)rintf((py + 1.f) * sc);
      int iz = (int)rintf((pz + 1.f) * sc);
      ix = min(max(ix, 2), up); iy = min(max(iy, 2), up); iz = min(max(iz, 2), up);
      sG[v2 * PG2 + s * 128 + j] =
          vols[s][(size_t)(ix + dx - 2) * dim * dim + (size_t)(iy + dy - 2) * dim + (iz + dz - 2)];
    }
  }
  __syncthreads();

  // ---- phase 2: conv 384 -> 128 (MFMA), out + bias -> sG cols 384..511 ----
  gemm_mfma<2, 12, 384, false>(sG, PG2, convH, convL, convb, w * 32,
                               sG + 384, PG2, lane);
  __syncthreads();

  // ---- phase 3: lfc 128 -> 128 (MFMA), out + bias -> sH cols 128..255 ----
  gemm_mfma<2, 4, 128, false>(sG + 384, PG2, lfcH, lfcL, lfcb, w * 32,
                              sH + 128, PH2, lane);
  __syncthreads();

  // ---- phase 4: fc2 256 -> 512 (MFMA), lrelu -> sG cols 0..511 (2x NT=4) ----
  gemm_mfma<4, 8, 256, true>(sH, PH2, fc2H, fc2L, fc2b, w * 128,
                             sG, PG2, lane);
  gemm_mfma<4, 8, 256, true>(sH, PH2, fc2H, fc2L, fc2b, w * 128 + 64,
                             sG, PG2, lane);
  __syncthreads();

  // ---- phase 5: fc3 512 -> 256 (MFMA), lrelu -> sH cols 0..255 ----
  gemm_mfma<4, 16, 512, true>(sG, PG2, fc3H, fc3L, fc3b, w * 64,
                              sH, PH2, lane);
  __syncthreads();

  // ---- phase 6: fc4 256 -> 3, x += 0.1*tanh ----
  if (tid < 48) {
    int v = tid / 3, c = tid % 3;
    float acc = fc4b[c];
    for (int k = 0; k < 256; ++k) acc += sH[v * PH2 + k] * fc4w[c * 256 + k];
    int vid = v0 + v;
    if (vid < NV) {
      float old = x[vid * 3 + c];
      x[vid * 3 + c] = old + 0.1f * tanhf(acc);
    }
  }
}

// ---------------- launch ----------------

extern "C" void kernel_launch(void* const* d_in, const int* in_sizes, int n_in,
                              void* d_out, int out_size, void* d_ws, size_t ws_size,
                              hipStream_t stream) {
  const float* v = (const float*)d_in[0];
  const int* f = (const int*)d_in[1];
  const float* vol0 = (const float*)d_in[2];
  const float* fc1w = (const float*)d_in[3];
  const float* fc1b = (const float*)d_in[4];
  const float* fc2w = (const float*)d_in[5];
  const float* fc2b = (const float*)d_in[6];
  const float* fc3w = (const float*)d_in[7];
  const float* fc3b = (const float*)d_in[8];
  const float* fc4w = (const float*)d_in[9];
  const float* fc4b = (const float*)d_in[10];
  const float* convw = (const float*)d_in[11];
  const float* convb = (const float*)d_in[12];
  const float* lfcw = (const float*)d_in[13];
  const float* lfcb = (const float*)d_in[14];
  const int* nsm = (const int*)d_in[15];

  float* ws = (float*)d_ws;
  float* x = ws;                  // 450000
  float* nrm = ws + 450000;       // 450000
  float* cnt = ws + 900000;       // 150000
  float* xs = ws + 1050000;       // 450000
  float* vol1 = ws + 1500000;     // 884736
  float* vol2 = ws + 2384736;     // 110592
  _Float16* w16 = (_Float16*)(ws + 2495328);
  _Float16* convH = w16;                 // 3*128*384 = 147456
  _Float16* convL = w16 + 147456;
  _Float16* lfcH = w16 + 294912;         // 3*16384
  _Float16* lfcL = w16 + 344064;
  _Float16* fc2H = w16 + 393216;         // 3*131072
  _Float16* fc2L = w16 + 786432;
  _Float16* fc3H = w16 + 1179648;        // 3*131072
  _Float16* fc3L = w16 + 1572864;

  hipMemcpyAsync(x, v, (size_t)NV * 3 * sizeof(float), hipMemcpyDeviceToDevice, stream);
  ds_kernel<<<3456, 256, 0, stream>>>(vol0, vol1, 96);
  ds_kernel<<<432, 256, 0, stream>>>(vol1, vol2, 48);
  hipMemsetAsync(cnt, 0, (size_t)NV * sizeof(float), stream);
  cnt_kernel<<<(NFACE + 255) / 256, 256, 0, stream>>>(f, cnt);

  // weight prep (hi/lo split), all 3 blocks at once
  wprep_conv_kernel<<<(3 * 128 * 384 + 255) / 256, 256, 0, stream>>>(convw, convH, convL);
  wprep_kernel<<<(3 * 16384 + 255) / 256, 256, 0, stream>>>(lfcw, lfcH, lfcL, 3 * 16384);
  wprep_kernel<<<(3 * 131072 + 255) / 256, 256, 0, stream>>>(fc2w, fc2H, fc2L, 3 * 131072);
  wprep_kernel<<<(3 * 131072 + 255) / 256, 256, 0, stream>>>(fc3w, fc3H, fc3L, 3 * 131072);

  const int nblk = (NV + MV - 1) / MV;  // 9375
  for (int b = 0; b < 3; ++b) {
    hipMemsetAsync(nrm, 0, (size_t)NV * 3 * sizeof(float), stream);
    face_normals_kernel<<<(NFACE + 255) / 256, 256, 0, stream>>>(x, f, nrm);
    block_kernel<<<nblk, NTHR, 0, stream>>>(
        x, nrm, vol0, vol1, vol2,
        fc1w + b * 128 * 6, fc1b + b * 128,
        convH + b * 49152, convL + b * 49152, convb + b * 128,
        lfcH + b * 16384, lfcL + b * 16384, lfcb + b * 128,
        fc2H + b * 131072, fc2L + b * 131072, fc2b + b * 512,
        fc3H + b * 131072, fc3L + b * 131072, fc3b + b * 256,
        fc4w + b * 768, fc4b + b * 3);
  }

  hipMemsetAsync(xs, 0, (size_t)NV * 3 * sizeof(float), stream);
  smooth_scatter_kernel<<<(NFACE + 255) / 256, 256, 0, stream>>>(x, f, xs);
  finalize_kernel<<<(NV * 3 + 255) / 256, 256, 0, stream>>>(xs, cnt, x, nsm, (float*)d_out);
}

// Round 14
// 4998.047 us; speedup vs baseline: 1.6031x; 1.0152x over previous
//
#include <hip/hip_runtime.h>
#include <math.h>

#define NV 150000
#define NFACE 300000
#define MV 16          // vertices per block
#define NTHR 512       // 8 waves, each owns 1/8 of N per GEMM phase

// LDS arena (f32 units)
#define PIN 9
#define PH2 268        // h row pitch (256 used + pad)
#define PG2 524        // g row pitch (512 used + pad)
#define OFF_IN 0                   // [16][9]
#define OFF_H 144                  // [16][268]
#define OFF_G (144 + 16*268)       // [16][524]  (cols 0..383 cubes, 384..511 xl1, then fc2 out)
#define ARENA (144 + 16*268 + 16*524)   // 12816 f32 = 51264 B -> 3 wg/CU (1536 thr, 153.8KB LDS)

typedef _Float16 h8v __attribute__((ext_vector_type(8)));
typedef float f4v __attribute__((ext_vector_type(4)));

// ---------------- small helper kernels ----------------

__global__ __launch_bounds__(256) void ds_kernel(const float* __restrict__ in,
                                                 float* __restrict__ out, int od) {
  int t = blockIdx.x * 256 + threadIdx.x;
  int tot = od * od * od;
  if (t >= tot) return;
  int oz = t % od; int r = t / od; int oy = r % od; int ox = r / od;
  int id = od * 2;
  size_t base = ((size_t)(2 * ox) * id + (size_t)(2 * oy)) * id + (size_t)(2 * oz);
  float s = 0.f;
  for (int i = 0; i < 2; ++i)
    for (int j = 0; j < 2; ++j)
      for (int k = 0; k < 2; ++k)
        s += in[base + (size_t)i * id * id + (size_t)j * id + k];
  out[t] = s * 0.125f;
}

__global__ __launch_bounds__(256) void face_normals_kernel(const float* __restrict__ x,
                                                           const int* __restrict__ f,
                                                           float* __restrict__ nrm) {
  int i = blockIdx.x * 256 + threadIdx.x;
  if (i >= NFACE) return;
  int a = f[i * 3 + 0], b = f[i * 3 + 1], c = f[i * 3 + 2];
  float ax = x[a * 3 + 0], ay = x[a * 3 + 1], az = x[a * 3 + 2];
  float bx = x[b * 3 + 0], by = x[b * 3 + 1], bz = x[b * 3 + 2];
  float cx = x[c * 3 + 0], cy = x[c * 3 + 1], cz = x[c * 3 + 2];
  float ux = bx - ax, uy = by - ay, uz = bz - az;
  float vx = cx - ax, vy = cy - ay, vz = cz - az;
  float nx = uy * vz - uz * vy;
  float ny = uz * vx - ux * vz;
  float nz = ux * vy - uy * vx;
  atomicAdd(&nrm[a * 3 + 0], nx); atomicAdd(&nrm[a * 3 + 1], ny); atomicAdd(&nrm[a * 3 + 2], nz);
  atomicAdd(&nrm[b * 3 + 0], nx); atomicAdd(&nrm[b * 3 + 1], ny); atomicAdd(&nrm[b * 3 + 2], nz);
  atomicAdd(&nrm[c * 3 + 0], nx); atomicAdd(&nrm[c * 3 + 1], ny); atomicAdd(&nrm[c * 3 + 2], nz);
}

__global__ __launch_bounds__(256) void cnt_kernel(const int* __restrict__ f,
                                                  float* __restrict__ cnt) {
  int i = blockIdx.x * 256 + threadIdx.x;
  if (i >= NFACE) return;
  atomicAdd(&cnt[f[i * 3 + 0]], 1.f);
  atomicAdd(&cnt[f[i * 3 + 1]], 1.f);
  atomicAdd(&cnt[f[i * 3 + 2]], 1.f);
}

__global__ __launch_bounds__(256) void smooth_scatter_kernel(const float* __restrict__ x,
                                                             const int* __restrict__ f,
                                                             float* __restrict__ xs) {
  int i = blockIdx.x * 256 + threadIdx.x;
  if (i >= NFACE) return;
  int a = f[i * 3 + 0], b = f[i * 3 + 1], c = f[i * 3 + 2];
  for (int d = 0; d < 3; ++d) atomicAdd(&xs[b * 3 + d], x[a * 3 + d]);
  for (int d = 0; d < 3; ++d) atomicAdd(&xs[c * 3 + d], x[b * 3 + d]);
  for (int d = 0; d < 3; ++d) atomicAdd(&xs[a * 3 + d], x[c * 3 + d]);
}

__global__ __launch_bounds__(256) void finalize_kernel(const float* __restrict__ xs,
                                                       const float* __restrict__ cnt,
                                                       const float* __restrict__ x,
                                                       const int* __restrict__ nsm,
                                                       float* __restrict__ out) {
  int e = blockIdx.x * 256 + threadIdx.x;
  if (e >= NV * 3) return;
  int ns = nsm[0];
  if (ns >= 1) {
    int v = e / 3;
    float c = fmaxf(cnt[v], 1.f);
    out[e] = xs[e] / c;
  } else {
    out[e] = x[e];
  }
}

// ---------------- weight prep: f32 -> f16 hi/lo planes ----------------

__global__ __launch_bounds__(256) void wprep_kernel(const float* __restrict__ src,
                                                    _Float16* __restrict__ hi,
                                                    _Float16* __restrict__ lo, int n) {
  int i = blockIdx.x * 256 + threadIdx.x;
  if (i >= n) return;
  float v = src[i];
  _Float16 h = (_Float16)v;
  hi[i] = h;
  lo[i] = (_Float16)(v - (float)h);
}

// conv weights: [3*128][375] (s*125+j) -> padded [3*128][384] (s*128+j, j>=125 zero)
__global__ __launch_bounds__(256) void wprep_conv_kernel(const float* __restrict__ src,
                                                         _Float16* __restrict__ hi,
                                                         _Float16* __restrict__ lo) {
  int i = blockIdx.x * 256 + threadIdx.x;
  const int tot = 3 * 128 * 384;
  if (i >= tot) return;
  int col = i % 384, row = i / 384;
  int s = col >> 7, j = col & 127;
  float v = (j < 125) ? src[row * 375 + s * 125 + j] : 0.f;
  _Float16 h = (_Float16)v;
  hi[i] = h;
  lo[i] = (_Float16)(v - (float)h);
}

// ---------------- fused deformation block with f16x3 MFMA GEMMs ----------------
// M=16 rows; each wave owns NT 16-col tiles at n0base, all 16 rows.
// (Register double-buffer retained from R13 — measured neutral, harmless.)

template <int NT, int KSTEPS, int K, bool ACT>
__device__ __forceinline__ void gemm_mfma(const float* __restrict__ Alds, int astride,
                                          const _Float16* __restrict__ WH,
                                          const _Float16* __restrict__ WL,
                                          const float* __restrict__ bias, int n0base,
                                          float* __restrict__ Olds, int ostride, int lane) {
  f4v acc[NT];
#pragma unroll
  for (int t = 0; t < NT; ++t) acc[t] = (f4v){0.f, 0.f, 0.f, 0.f};
  const int r16 = lane & 15, kq = lane >> 4;
  const float* arow = Alds + r16 * astride + kq * 8;
  const _Float16* wh = WH + (size_t)(n0base + r16) * K + kq * 8;
  const _Float16* wl = WL + (size_t)(n0base + r16) * K + kq * 8;

  // prologue: fetch k0 = 0
  float4 aA = *(const float4*)(arow);
  float4 aB = *(const float4*)(arow + 4);
  h8v bh[NT], bl[NT];
#pragma unroll
  for (int t = 0; t < NT; ++t) {
    bh[t] = *(const h8v*)(wh + (size_t)t * 16 * K);
    bl[t] = *(const h8v*)(wl + (size_t)t * 16 * K);
  }

#pragma unroll
  for (int k0 = 0; k0 < KSTEPS; ++k0) {
    // prefetch k0+1 while MFMAs of k0 run below
    float4 aA2, aB2;
    h8v bh2[NT], bl2[NT];
    if (k0 + 1 < KSTEPS) {
      aA2 = *(const float4*)(arow + (k0 + 1) * 32);
      aB2 = *(const float4*)(arow + (k0 + 1) * 32 + 4);
#pragma unroll
      for (int t = 0; t < NT; ++t) {
        bh2[t] = *(const h8v*)(wh + (size_t)t * 16 * K + (k0 + 1) * 32);
        bl2[t] = *(const h8v*)(wl + (size_t)t * 16 * K + (k0 + 1) * 32);
      }
    }
    // convert current A to hi/lo f16
    float av[8] = {aA.x, aA.y, aA.z, aA.w, aB.x, aB.y, aB.z, aB.w};
    h8v ah, al;
#pragma unroll
    for (int e = 0; e < 8; ++e) {
      _Float16 h = (_Float16)av[e];
      ah[e] = h;
      al[e] = (_Float16)(av[e] - (float)h);
    }
#pragma unroll
    for (int t = 0; t < NT; ++t) {
      acc[t] = __builtin_amdgcn_mfma_f32_16x16x32_f16(ah, bh[t], acc[t], 0, 0, 0);
      acc[t] = __builtin_amdgcn_mfma_f32_16x16x32_f16(al, bh[t], acc[t], 0, 0, 0);
      acc[t] = __builtin_amdgcn_mfma_f32_16x16x32_f16(ah, bl[t], acc[t], 0, 0, 0);
    }
    if (k0 + 1 < KSTEPS) {
      aA = aA2; aB = aB2;
#pragma unroll
      for (int t = 0; t < NT; ++t) { bh[t] = bh2[t]; bl[t] = bl2[t]; }
    }
  }
#pragma unroll
  for (int t = 0; t < NT; ++t) {
    int n = n0base + t * 16 + r16;
    float b = bias[n];
#pragma unroll
    for (int r = 0; r < 4; ++r) {
      int row = kq * 4 + r;
      float v = acc[t][r] + b;
      if (ACT) v = (v >= 0.f) ? v : 0.15f * v;
      Olds[row * ostride + n] = v;
    }
  }
}

__global__ __launch_bounds__(512, 6) void block_kernel(
    float* __restrict__ x, const float* __restrict__ nrm,
    const float* __restrict__ vol0, const float* __restrict__ vol1, const float* __restrict__ vol2,
    const float* __restrict__ fc1w, const float* __restrict__ fc1b,
    const _Float16* __restrict__ convH, const _Float16* __restrict__ convL,
    const float* __restrict__ convb,
    const _Float16* __restrict__ lfcH, const _Float16* __restrict__ lfcL,
    const float* __restrict__ lfcb,
    const _Float16* __restrict__ fc2H, const _Float16* __restrict__ fc2L,
    const float* __restrict__ fc2b,
    const _Float16* __restrict__ fc3H, const _Float16* __restrict__ fc3L,
    const float* __restrict__ fc3b,
    const float* __restrict__ fc4w, const float* __restrict__ fc4b) {
  __shared__ float S[ARENA];
  float* sIn = S + OFF_IN;   // [16][9]
  float* sH = S + OFF_H;     // [16][268]
  float* sG = S + OFF_G;     // [16][524]

  const int tid = threadIdx.x;
  const int v0 = blockIdx.x * MV;
  const int w = tid >> 6;    // wave 0..7 -> N-octant
  const int lane = tid & 63;

  // ---- phase 0: stage inputs (clamped for the partial last tile) ----
  if (tid < MV) {
    int vid = min(v0 + tid, NV - 1);
    float px = x[vid * 3 + 0], py = x[vid * 3 + 1], pz = x[vid * 3 + 2];
    float nx = nrm[vid * 3 + 0], ny = nrm[vid * 3 + 1], nz = nrm[vid * 3 + 2];
    float nn = sqrtf(nx * nx + ny * ny + nz * nz);
    float d = fmaxf(nn, 1e-12f);
    sIn[tid * PIN + 0] = px; sIn[tid * PIN + 1] = py; sIn[tid * PIN + 2] = pz;
    sIn[tid * PIN + 3] = nx / d; sIn[tid * PIN + 4] = ny / d; sIn[tid * PIN + 5] = nz / d;
  }
  __syncthreads();

  // ---- phase 1: fc1 (f32 VALU) + cube gather (both read only sIn) ----
  {
    // fc1: 6 -> 128, lrelu -> sH cols 0..127. thread: vertex tid>>5, 4 channels.
    int v = tid >> 5;          // 0..15
    int c0 = (tid & 31) * 4;   // 0..124
    float in6[6];
#pragma unroll
    for (int k = 0; k < 6; ++k) in6[k] = sIn[v * PIN + k];
#pragma unroll
    for (int j = 0; j < 4; ++j) {
      int c = c0 + j;
      float a = fc1b[c];
#pragma unroll
      for (int k = 0; k < 6; ++k) a += in6[k] * fc1w[c * 6 + k];
      sH[v * PH2 + c] = (a >= 0.f) ? a : 0.15f * a;
    }
    // zero the conv K-pad columns (s*128+125..127): 3 scales x 16 verts x 3 cols = 144
    if (tid < 144) {
      int s = tid / 48, rem = tid % 48;
      int vz = rem / 3, jj = 125 + rem % 3;
      sG[vz * PG2 + s * 128 + jj] = 0.f;
    }
    // gather: 3 scales x 16 verts x 125 samples -> sG cols [s*128 + j]
    const float* vols[3] = {vol0, vol1, vol2};
    const int dims[3] = {192, 96, 48};
    const float scl[3] = {96.f, 48.f, 24.f};
    const int ups[3] = {189, 93, 45};
    for (int t = tid; t < 6000; t += NTHR) {
      int s = t / 2000;
      int rem = t - s * 2000;
      int v2 = rem / 125;
      int j = rem - v2 * 125;
      int dx = j / 25; int r2 = j - dx * 25; int dy = r2 / 5; int dz = r2 - dy * 5;
      float px = sIn[v2 * PIN + 0], py = sIn[v2 * PIN + 1], pz = sIn[v2 * PIN + 2];
      float sc = scl[s];
      int up = ups[s];
      int dim = dims[s];
      int ix = (int)rintf((px + 1.f) * sc);
      int iy = (int)rintf((py + 1.f) * sc);
      int iz = (int)rintf((pz + 1.f) * sc);
      ix = min(max(ix, 2), up); iy = min(max(iy, 2), up); iz = min(max(iz, 2), up);
      sG[v2 * PG2 + s * 128 + j] =
          vols[s][(size_t)(ix + dx - 2) * dim * dim + (size_t)(iy + dy - 2) * dim + (iz + dz - 2)];
    }
  }
  __syncthreads();

  // ---- phase 2: conv 384 -> 128 (MFMA), out + bias -> sG cols 384..511 ----
  gemm_mfma<1, 12, 384, false>(sG, PG2, convH, convL, convb, w * 16,
                               sG + 384, PG2, lane);
  __syncthreads();

  // ---- phase 3: lfc 128 -> 128 (MFMA), out + bias -> sH cols 128..255 ----
  gemm_mfma<1, 4, 128, false>(sG + 384, PG2, lfcH, lfcL, lfcb, w * 16,
                              sH + 128, PH2, lane);
  __syncthreads();

  // ---- phase 4: fc2 256 -> 512 (MFMA), lrelu -> sG cols 0..511 ----
  gemm_mfma<4, 8, 256, true>(sH, PH2, fc2H, fc2L, fc2b, w * 64,
                             sG, PG2, lane);
  __syncthreads();

  // ---- phase 5: fc3 512 -> 256 (MFMA), lrelu -> sH cols 0..255 ----
  gemm_mfma<2, 16, 512, true>(sG, PG2, fc3H, fc3L, fc3b, w * 32,
                              sH, PH2, lane);
  __syncthreads();

  // ---- phase 6: fc4 256 -> 3, x += 0.1*tanh ----
  if (tid < 48) {
    int v = tid / 3, c = tid % 3;
    float acc = fc4b[c];
    for (int k = 0; k < 256; ++k) acc += sH[v * PH2 + k] * fc4w[c * 256 + k];
    int vid = v0 + v;
    if (vid < NV) {
      float old = x[vid * 3 + c];
      x[vid * 3 + c] = old + 0.1f * tanhf(acc);
    }
  }
}

// ---------------- launch ----------------

extern "C" void kernel_launch(void* const* d_in, const int* in_sizes, int n_in,
                              void* d_out, int out_size, void* d_ws, size_t ws_size,
                              hipStream_t stream) {
  const float* v = (const float*)d_in[0];
  const int* f = (const int*)d_in[1];
  const float* vol0 = (const float*)d_in[2];
  const float* fc1w = (const float*)d_in[3];
  const float* fc1b = (const float*)d_in[4];
  const float* fc2w = (const float*)d_in[5];
  const float* fc2b = (const float*)d_in[6];
  const float* fc3w = (const float*)d_in[7];
  const float* fc3b = (const float*)d_in[8];
  const float* fc4w = (const float*)d_in[9];
  const float* fc4b = (const float*)d_in[10];
  const float* convw = (const float*)d_in[11];
  const float* convb = (const float*)d_in[12];
  const float* lfcw = (const float*)d_in[13];
  const float* lfcb = (const float*)d_in[14];
  const int* nsm = (const int*)d_in[15];

  float* ws = (float*)d_ws;
  float* x = ws;                  // 450000
  float* nrm = ws + 450000;       // 450000
  float* cnt = ws + 900000;       // 150000
  float* xs = ws + 1050000;       // 450000
  float* vol1 = ws + 1500000;     // 884736
  float* vol2 = ws + 2384736;     // 110592
  _Float16* w16 = (_Float16*)(ws + 2495328);
  _Float16* convH = w16;                 // 3*128*384 = 147456
  _Float16* convL = w16 + 147456;
  _Float16* lfcH = w16 + 294912;         // 3*16384
  _Float16* lfcL = w16 + 344064;
  _Float16* fc2H = w16 + 393216;         // 3*131072
  _Float16* fc2L = w16 + 786432;
  _Float16* fc3H = w16 + 1179648;        // 3*131072
  _Float16* fc3L = w16 + 1572864;

  hipMemcpyAsync(x, v, (size_t)NV * 3 * sizeof(float), hipMemcpyDeviceToDevice, stream);
  ds_kernel<<<3456, 256, 0, stream>>>(vol0, vol1, 96);
  ds_kernel<<<432, 256, 0, stream>>>(vol1, vol2, 48);
  hipMemsetAsync(cnt, 0, (size_t)NV * sizeof(float), stream);
  cnt_kernel<<<(NFACE + 255) / 256, 256, 0, stream>>>(f, cnt);

  // weight prep (hi/lo split), all 3 blocks at once
  wprep_conv_kernel<<<(3 * 128 * 384 + 255) / 256, 256, 0, stream>>>(convw, convH, convL);
  wprep_kernel<<<(3 * 16384 + 255) / 256, 256, 0, stream>>>(lfcw, lfcH, lfcL, 3 * 16384);
  wprep_kernel<<<(3 * 131072 + 255) / 256, 256, 0, stream>>>(fc2w, fc2H, fc2L, 3 * 131072);
  wprep_kernel<<<(3 * 131072 + 255) / 256, 256, 0, stream>>>(fc3w, fc3H, fc3L, 3 * 131072);

  const int nblk = (NV + MV - 1) / MV;  // 9375
  for (int b = 0; b < 3; ++b) {
    hipMemsetAsync(nrm, 0, (size_t)NV * 3 * sizeof(float), stream);
    face_normals_kernel<<<(NFACE + 255) / 256, 256, 0, stream>>>(x, f, nrm);
    block_kernel<<<nblk, NTHR, 0, stream>>>(
        x, nrm, vol0, vol1, vol2,
        fc1w + b * 128 * 6, fc1b + b * 128,
        convH + b * 49152, convL + b * 49152, convb + b * 128,
        lfcH + b * 16384, lfcL + b * 16384, lfcb + b * 128,
        fc2H + b * 131072, fc2L + b * 131072, fc2b + b * 512,
        fc3H + b * 131072, fc3L + b * 131072, fc3b + b * 256,
        fc4w + b * 768, fc4b + b * 3);
  }

  hipMemsetAsync(xs, 0, (size_t)NV * 3 * sizeof(float), stream);
  smooth_scatter_kernel<<<(NFACE + 255) / 256, 256, 0, stream>>>(x, f, xs);
  finalize_kernel<<<(NV * 3 + 255) / 256, 256, 0, stream>>>(xs, cnt, x, nsm, (float*)d_out);
}